// Round 6
// baseline (753.891 us; speedup 1.0000x reference)
//
#include <hip/hip_runtime.h>
#include <hip/hip_bf16.h>

#define D 64
#define RPB 128          // rows per bucket (row_local fits in 7 bits)
#define NBMAX 1024       // max buckets; needs n_nodes <= 131072 (17-bit col)

// ===========================================================================
// support = x @ (W0+W1+W2), stored as bf16 (halves gather traffic + ws size)
// ===========================================================================
__global__ __launch_bounds__(256) void gemm_kernel(const float* __restrict__ x,
                                                   const float* __restrict__ w0,
                                                   const float* __restrict__ w1,
                                                   const float* __restrict__ w2,
                                                   __hip_bfloat16* __restrict__ support,
                                                   int n) {
    __shared__ float Ws[D * D];
    __shared__ float xs[4][D];

    for (int i = threadIdx.x; i < D * D; i += 256)
        Ws[i] = w0[i] + w1[i] + w2[i];
    __syncthreads();

    const int wid  = threadIdx.x >> 6;
    const int lane = threadIdx.x & 63;
    int row = blockIdx.x * 4 + wid;
    const int nw = gridDim.x * 4;

    for (; row < n; row += nw) {
        xs[wid][lane] = x[(size_t)row * D + lane];
        float acc = 0.0f;
#pragma unroll
        for (int k = 0; k < D; ++k) {
            acc += xs[wid][k] * Ws[k * D + lane];
        }
        support[(size_t)row * D + lane] = __float2bfloat16(acc);
    }
}

// f32-support variant for the fallback path
__global__ __launch_bounds__(256) void gemm_f32_kernel(const float* __restrict__ x,
                                                       const float* __restrict__ w0,
                                                       const float* __restrict__ w1,
                                                       const float* __restrict__ w2,
                                                       float* __restrict__ support,
                                                       int n) {
    __shared__ float Ws[D * D];
    __shared__ float xs[4][D];
    for (int i = threadIdx.x; i < D * D; i += 256)
        Ws[i] = w0[i] + w1[i] + w2[i];
    __syncthreads();
    const int wid  = threadIdx.x >> 6;
    const int lane = threadIdx.x & 63;
    int row = blockIdx.x * 4 + wid;
    const int nw = gridDim.x * 4;
    for (; row < n; row += nw) {
        xs[wid][lane] = x[(size_t)row * D + lane];
        float acc = 0.0f;
#pragma unroll
        for (int k = 0; k < D; ++k) acc += xs[wid][k] * Ws[k * D + lane];
        support[(size_t)row * D + lane] = acc;
    }
}

// ===========================================================================
// Coarse binning: hist -> scan -> partition scatter (grouped by 128-row bucket)
// ===========================================================================
__global__ __launch_bounds__(256) void zero_kernel(int* __restrict__ p, int n) {
    int i = blockIdx.x * 256 + threadIdx.x;
    int stride = gridDim.x * 256;
    for (; i < n; i += stride) p[i] = 0;
}

__global__ __launch_bounds__(256) void bucket_hist_kernel(const int* __restrict__ rows,
                                                          int ne, int* __restrict__ gcnt,
                                                          int nb) {
    __shared__ int lcnt[NBMAX];
    for (int i = threadIdx.x; i < nb; i += 256) lcnt[i] = 0;
    __syncthreads();
    int i = blockIdx.x * 256 + threadIdx.x;
    int stride = gridDim.x * 256;
    for (; i < ne; i += stride) atomicAdd(&lcnt[rows[i] >> 7], 1);
    __syncthreads();
    for (int b = threadIdx.x; b < nb; b += 256) {
        int c = lcnt[b];
        if (c) atomicAdd(&gcnt[b], c);
    }
}

// 1 block: exclusive scan of gcnt -> base[nb+1], cursor copy
__global__ __launch_bounds__(256) void bucket_scan_kernel(const int* __restrict__ gcnt,
                                                          int nb,
                                                          int* __restrict__ base,
                                                          int* __restrict__ cursor) {
    __shared__ int ts[256];
    const int tid = threadIdx.x;
    int b0 = tid * 4;
    int v[4]; int tsum = 0;
#pragma unroll
    for (int j = 0; j < 4; ++j) {
        int idx = b0 + j;
        v[j] = (idx < nb) ? gcnt[idx] : 0;
        tsum += v[j];
    }
    ts[tid] = tsum;
    __syncthreads();
    for (int off = 1; off < 256; off <<= 1) {
        int t = (tid >= off) ? ts[tid - off] : 0;
        __syncthreads();
        ts[tid] += t;
        __syncthreads();
    }
    int excl = ts[tid] - tsum;
#pragma unroll
    for (int j = 0; j < 4; ++j) {
        int idx = b0 + j;
        if (idx < nb) { base[idx] = excl; cursor[idx] = excl; }
        excl += v[j];
    }
    if (tid == 255) base[nb] = excl;
}

// Each block: local hist over its edge chunk -> reserve bucket runs -> scatter
// packed (row_local<<17 | col, val). Run lines stay L2-resident per block.
__global__ __launch_bounds__(256) void bin_scatter_kernel(const int* __restrict__ rows,
                                                          const int* __restrict__ cols,
                                                          const float* __restrict__ vals,
                                                          int ne,
                                                          int* __restrict__ cursor,
                                                          int nb,
                                                          int2* __restrict__ binned) {
    __shared__ int lcnt[NBMAX];
    __shared__ int lbase[NBMAX];
    const int tid = threadIdx.x;
    const int ce = (ne + gridDim.x - 1) / gridDim.x;
    const int e0 = blockIdx.x * ce;
    const int e1 = min(ne, e0 + ce);

    for (int i = tid; i < nb; i += 256) lcnt[i] = 0;
    __syncthreads();
    for (int e = e0 + tid; e < e1; e += 256) atomicAdd(&lcnt[rows[e] >> 7], 1);
    __syncthreads();
    for (int b = tid; b < nb; b += 256) {
        int c = lcnt[b];
        lbase[b] = c ? atomicAdd(&cursor[b], c) : 0;
    }
    __syncthreads();
    for (int i = tid; i < nb; i += 256) lcnt[i] = 0;   // reuse as local cursor
    __syncthreads();
    for (int e = e0 + tid; e < e1; e += 256) {
        int r = rows[e];
        int b = r >> 7;
        int loc = atomicAdd(&lcnt[b], 1);
        int2 cv;
        cv.x = ((r & (RPB - 1)) << 17) | cols[e];
        cv.y = __float_as_int(vals[e]);
        binned[lbase[b] + loc] = cv;
    }
}

// ===========================================================================
// Fused accumulate: one 512-thread block per 128-row bucket. 32 KB LDS f32
// accumulator. 8 waves stream contiguous segments of the bucket's (unsorted)
// edge list: uniform int2 load -> coalesced 2B/lane bf16 gather (pattern of
// the verified 67us pull) -> **unsafeAtomicAdd -> HW ds_add_f32** (the R3/R5
// disasters were plain atomicAdd lowering to a CAS retry loop on LDS).
// ===========================================================================
__global__ __launch_bounds__(512) void accumulate_kernel(const int* __restrict__ base,
                                                         const int2* __restrict__ binned,
                                                         const __hip_bfloat16* __restrict__ sup,
                                                         const float* __restrict__ bias,
                                                         float* __restrict__ out,
                                                         int n) {
    __shared__ float acc[RPB * D];   // 32 KB
    const int tid  = threadIdx.x;
    const int lane = tid & 63;
    const int wid  = tid >> 6;       // 0..7
    const int b    = blockIdx.x;

    for (int i = tid; i < RPB * D; i += 512) acc[i] = 0.0f;
    __syncthreads();

    const int jb = base[b], je = base[b + 1];
    const int nedge = je - jb;
    const int seg = (nedge + 7) >> 3;
    const int js = jb + wid * seg;
    const int jend = min(je, js + seg);

    int j = js;
    for (; j + 8 <= jend; j += 8) {
        int2 e[8];
#pragma unroll
        for (int u = 0; u < 8; ++u) e[u] = binned[j + u];
        float s[8];
#pragma unroll
        for (int u = 0; u < 8; ++u)
            s[u] = __bfloat162float(sup[(size_t)(e[u].x & 0x1FFFF) * D + lane]);
#pragma unroll
        for (int u = 0; u < 8; ++u)
            unsafeAtomicAdd(&acc[(e[u].x >> 17) * D + lane],
                            __int_as_float(e[u].y) * s[u]);
    }
    for (; j < jend; ++j) {
        int2 e = binned[j];
        float s = __bfloat162float(sup[(size_t)(e.x & 0x1FFFF) * D + lane]);
        unsafeAtomicAdd(&acc[(e.x >> 17) * D + lane], __int_as_float(e.y) * s);
    }
    __syncthreads();

    const float bl = bias[lane];
    const int row0 = b * RPB;
    for (int i = wid; i < RPB; i += 8) {
        int r = row0 + i;
        if (r < n) out[(size_t)r * D + lane] = acc[i * D + lane] + bl;
    }
}

// ===========================================================================
// Fallback (R1, verified): bias-init + atomic scatter (f32 support)
// ===========================================================================
__global__ __launch_bounds__(256) void init_kernel(const float* __restrict__ bias,
                                                   float* __restrict__ out, int total4) {
    int i = blockIdx.x * 256 + threadIdx.x;
    int stride = gridDim.x * 256;
    for (; i < total4; i += stride) {
        int base4 = (i * 4) & (D - 1);
        float4 bv;
        bv.x = bias[base4 + 0]; bv.y = bias[base4 + 1];
        bv.z = bias[base4 + 2]; bv.w = bias[base4 + 3];
        reinterpret_cast<float4*>(out)[i] = bv;
    }
}

__global__ __launch_bounds__(256) void scatter_kernel(const int* __restrict__ rows,
                                                      const int* __restrict__ cols,
                                                      const float* __restrict__ vals,
                                                      const float* __restrict__ support,
                                                      float* __restrict__ out, int ne) {
    const int wid  = blockIdx.x * 4 + (threadIdx.x >> 6);
    const int lane = threadIdx.x & 63;
    const int nw = gridDim.x * 4;
    for (int e = wid; e < ne; e += nw) {
        const int r = rows[e];
        const int c = cols[e];
        const float v = vals[e];
        unsafeAtomicAdd(&out[(size_t)r * D + lane], v * support[(size_t)c * D + lane]);
    }
}

extern "C" void kernel_launch(void* const* d_in, const int* in_sizes, int n_in,
                              void* d_out, int out_size, void* d_ws, size_t ws_size,
                              hipStream_t stream) {
    const float* x         = (const float*)d_in[0];
    const int*   edge_rows = (const int*)d_in[1];
    const int*   edge_cols = (const int*)d_in[2];
    const float* edge_vals = (const float*)d_in[3];
    const float* w_own     = (const float*)d_in[4];
    const float* w_nbr     = (const float*)d_in[5];
    const float* w_temp    = (const float*)d_in[6];
    const float* bias      = (const float*)d_in[7];

    float* out = (float*)d_out;
    const int n_nodes = in_sizes[0] / D;
    const int n_edges = in_sizes[1];
    const int nb = (n_nodes + RPB - 1) / RPB;

    // ---- workspace layout ----
    char* ws = (char*)d_ws;
    size_t off = 0;
    auto take = [&](size_t bytes) -> char* {
        char* p = ws + off;
        off = (off + bytes + 15) & ~(size_t)15;
        return p;
    };
    __hip_bfloat16* support = (__hip_bfloat16*)take((size_t)n_nodes * D * sizeof(__hip_bfloat16));
    int2* binned = (int2*)take((size_t)n_edges * sizeof(int2));
    int*  gcnt   = (int*) take((size_t)nb * sizeof(int));
    int*  base   = (int*) take((size_t)(nb + 1) * sizeof(int));
    int*  cursor = (int*) take((size_t)nb * sizeof(int));
    const bool full_fits = (off <= ws_size) && (nb <= NBMAX) && (n_nodes <= (1 << 17));

    if (full_fits) {
        gemm_kernel<<<1024, 256, 0, stream>>>(x, w_own, w_nbr, w_temp, support, n_nodes);
        zero_kernel<<<4, 256, 0, stream>>>(gcnt, nb);
        bucket_hist_kernel<<<512, 256, 0, stream>>>(edge_rows, n_edges, gcnt, nb);
        bucket_scan_kernel<<<1, 256, 0, stream>>>(gcnt, nb, base, cursor);
        bin_scatter_kernel<<<512, 256, 0, stream>>>(edge_rows, edge_cols, edge_vals,
                                                    n_edges, cursor, nb, binned);
        accumulate_kernel<<<nb, 512, 0, stream>>>(base, binned, support, bias, out, n_nodes);
    } else {
        // R1 fallback: f32 support + atomic scatter
        float* support_f = (float*)d_ws;
        gemm_f32_kernel<<<1024, 256, 0, stream>>>(x, w_own, w_nbr, w_temp, support_f, n_nodes);
        int total4 = (n_nodes * D) / 4;
        int blocks = (total4 + 255) / 256; if (blocks > 2048) blocks = 2048;
        init_kernel<<<blocks, 256, 0, stream>>>(bias, out, total4);
        scatter_kernel<<<2048, 256, 0, stream>>>(edge_rows, edge_cols, edge_vals,
                                                 support_f, out, n_edges);
    }
}

// Round 7
// 139.103 us; speedup vs baseline: 5.4197x; 5.4197x over previous
//
#include <hip/hip_runtime.h>
#include <hip/hip_bf16.h>

#define D 64
#define RPB 128          // rows per bucket (row_local fits in 7 bits)
#define NBMAX 1024       // max buckets; needs n_nodes <= 131072 (17-bit col)

// ===========================================================================
// support = x @ (W0+W1+W2), stored as bf16 (halves gather traffic + ws size)
// ===========================================================================
__global__ __launch_bounds__(256) void gemm_kernel(const float* __restrict__ x,
                                                   const float* __restrict__ w0,
                                                   const float* __restrict__ w1,
                                                   const float* __restrict__ w2,
                                                   __hip_bfloat16* __restrict__ support,
                                                   int n) {
    __shared__ float Ws[D * D];
    __shared__ float xs[4][D];

    for (int i = threadIdx.x; i < D * D; i += 256)
        Ws[i] = w0[i] + w1[i] + w2[i];
    __syncthreads();

    const int wid  = threadIdx.x >> 6;
    const int lane = threadIdx.x & 63;
    int row = blockIdx.x * 4 + wid;
    const int nw = gridDim.x * 4;

    for (; row < n; row += nw) {
        xs[wid][lane] = x[(size_t)row * D + lane];
        float acc = 0.0f;
#pragma unroll
        for (int k = 0; k < D; ++k) {
            acc += xs[wid][k] * Ws[k * D + lane];
        }
        support[(size_t)row * D + lane] = __float2bfloat16(acc);
    }
}

// f32-support variant for the fallback path
__global__ __launch_bounds__(256) void gemm_f32_kernel(const float* __restrict__ x,
                                                       const float* __restrict__ w0,
                                                       const float* __restrict__ w1,
                                                       const float* __restrict__ w2,
                                                       float* __restrict__ support,
                                                       int n) {
    __shared__ float Ws[D * D];
    __shared__ float xs[4][D];
    for (int i = threadIdx.x; i < D * D; i += 256)
        Ws[i] = w0[i] + w1[i] + w2[i];
    __syncthreads();
    const int wid  = threadIdx.x >> 6;
    const int lane = threadIdx.x & 63;
    int row = blockIdx.x * 4 + wid;
    const int nw = gridDim.x * 4;
    for (; row < n; row += nw) {
        xs[wid][lane] = x[(size_t)row * D + lane];
        float acc = 0.0f;
#pragma unroll
        for (int k = 0; k < D; ++k) acc += xs[wid][k] * Ws[k * D + lane];
        support[(size_t)row * D + lane] = acc;
    }
}

// ===========================================================================
// Coarse binning: hist -> scan -> partition scatter (grouped by 128-row bucket)
// ===========================================================================
__global__ __launch_bounds__(256) void zero_kernel(int* __restrict__ p, int n) {
    int i = blockIdx.x * 256 + threadIdx.x;
    int stride = gridDim.x * 256;
    for (; i < n; i += stride) p[i] = 0;
}

__global__ __launch_bounds__(256) void bucket_hist_kernel(const int* __restrict__ rows,
                                                          int ne, int* __restrict__ gcnt,
                                                          int nb) {
    __shared__ int lcnt[NBMAX];
    for (int i = threadIdx.x; i < nb; i += 256) lcnt[i] = 0;
    __syncthreads();
    int i = blockIdx.x * 256 + threadIdx.x;
    int stride = gridDim.x * 256;
    for (; i < ne; i += stride) atomicAdd(&lcnt[rows[i] >> 7], 1);
    __syncthreads();
    for (int b = threadIdx.x; b < nb; b += 256) {
        int c = lcnt[b];
        if (c) atomicAdd(&gcnt[b], c);
    }
}

// 1 block: exclusive scan of gcnt -> base[nb+1], cursor copy
__global__ __launch_bounds__(256) void bucket_scan_kernel(const int* __restrict__ gcnt,
                                                          int nb,
                                                          int* __restrict__ base,
                                                          int* __restrict__ cursor) {
    __shared__ int ts[256];
    const int tid = threadIdx.x;
    int b0 = tid * 4;
    int v[4]; int tsum = 0;
#pragma unroll
    for (int j = 0; j < 4; ++j) {
        int idx = b0 + j;
        v[j] = (idx < nb) ? gcnt[idx] : 0;
        tsum += v[j];
    }
    ts[tid] = tsum;
    __syncthreads();
    for (int off = 1; off < 256; off <<= 1) {
        int t = (tid >= off) ? ts[tid - off] : 0;
        __syncthreads();
        ts[tid] += t;
        __syncthreads();
    }
    int excl = ts[tid] - tsum;
#pragma unroll
    for (int j = 0; j < 4; ++j) {
        int idx = b0 + j;
        if (idx < nb) { base[idx] = excl; cursor[idx] = excl; }
        excl += v[j];
    }
    if (tid == 255) base[nb] = excl;
}

// Each block: local hist over its edge chunk -> reserve bucket runs -> scatter
// packed (row_local<<17 | col, val). 256 blocks -> ~6250-edge chunks -> avg
// 8 edges (64 B = one full line) per (block,bucket) run: line-granular writes.
__global__ __launch_bounds__(256) void bin_scatter_kernel(const int* __restrict__ rows,
                                                          const int* __restrict__ cols,
                                                          const float* __restrict__ vals,
                                                          int ne,
                                                          int* __restrict__ cursor,
                                                          int nb,
                                                          int2* __restrict__ binned) {
    __shared__ int lcnt[NBMAX];
    __shared__ int lbase[NBMAX];
    const int tid = threadIdx.x;
    const int ce = (ne + gridDim.x - 1) / gridDim.x;
    const int e0 = blockIdx.x * ce;
    const int e1 = min(ne, e0 + ce);

    for (int i = tid; i < nb; i += 256) lcnt[i] = 0;
    __syncthreads();
    for (int e = e0 + tid; e < e1; e += 256) atomicAdd(&lcnt[rows[e] >> 7], 1);
    __syncthreads();
    for (int b = tid; b < nb; b += 256) {
        int c = lcnt[b];
        lbase[b] = c ? atomicAdd(&cursor[b], c) : 0;
    }
    __syncthreads();
    for (int i = tid; i < nb; i += 256) lcnt[i] = 0;   // reuse as local cursor
    __syncthreads();
    for (int e = e0 + tid; e < e1; e += 256) {
        int r = rows[e];
        int b = r >> 7;
        int loc = atomicAdd(&lcnt[b], 1);
        int2 cv;
        cv.x = ((r & (RPB - 1)) << 17) | cols[e];
        cv.y = __float_as_int(vals[e]);
        binned[lbase[b] + loc] = cv;
    }
}

// ===========================================================================
// local_csr: one block per bucket. LDS 128-row hist + scan, write rowptr,
// then scatter binned -> csr sorted by row (contiguous 16 KB window, L2-hot).
// ===========================================================================
__global__ __launch_bounds__(256) void local_csr_kernel(const int* __restrict__ base,
                                                        const int2* __restrict__ binned,
                                                        int* __restrict__ rowptr,
                                                        int2* __restrict__ csr,
                                                        int n) {
    __shared__ int lh[RPB];
    __shared__ int lp[RPB];
    const int tid = threadIdx.x;
    const int b = blockIdx.x;
    const int jb = base[b], je = base[b + 1];

    for (int i = tid; i < RPB; i += 256) lh[i] = 0;
    __syncthreads();
    for (int j = jb + tid; j < je; j += 256) atomicAdd(&lh[binned[j].x >> 17], 1);
    __syncthreads();
    if (tid < RPB) lp[tid] = lh[tid];
    __syncthreads();
    for (int off = 1; off < RPB; off <<= 1) {
        int t = (tid < RPB && tid >= off) ? lp[tid - off] : 0;
        __syncthreads();
        if (tid < RPB) lp[tid] += t;
        __syncthreads();
    }
    if (tid < RPB) {
        int excl = lp[tid] - lh[tid];
        int start = jb + excl;
        lh[tid] = start;                 // becomes cursor
        int r = b * RPB + tid;
        if (r < n) rowptr[r] = start;
    }
    __syncthreads();
    for (int j = jb + tid; j < je; j += 256) {
        int2 e = binned[j];
        int rl = e.x >> 17;
        int pos = atomicAdd(&lh[rl], 1);
        int2 o; o.x = e.x & 0x1FFFF; o.y = e.y;
        csr[pos] = o;
    }
}

// ===========================================================================
// Pull v2: 2 rows per wave. lane 0-31 = row 2w, lane 32-63 = row 2w+1;
// each lane loads a uint (2 bf16 features) -> 32-lane 128 B coalesced gather,
// two independent row streams per wave (2x outstanding loads vs v1).
// Register accumulate, 4-deep unroll, no atomics.
// ===========================================================================
__global__ __launch_bounds__(256) void pull2_kernel(const int* __restrict__ rowptr,
                                                    const int2* __restrict__ csr,
                                                    const unsigned int* __restrict__ sup32,
                                                    const float* __restrict__ bias,
                                                    float* __restrict__ out, int n) {
    const int tid  = threadIdx.x;
    const int lane = tid & 63;
    const int half = lane >> 5;          // 0/1 -> which row of the pair
    const int sub  = lane & 31;          // feature pair index
    const int wave = blockIdx.x * 4 + (tid >> 6);
    const int nwave = gridDim.x * 4;
    const float2 b2 = reinterpret_cast<const float2*>(bias)[sub];

    for (int w = wave; 2 * w < n; w += nwave) {
        const int r = 2 * w + half;
        float ax = 0.0f, ay = 0.0f;
        if (r < n) {
            int jb = rowptr[r], je = rowptr[r + 1];
            int j = jb;
            for (; j + 3 < je; j += 4) {
                int2 e0 = csr[j], e1 = csr[j + 1], e2 = csr[j + 2], e3 = csr[j + 3];
                unsigned int u0 = sup32[(size_t)e0.x * 32 + sub];
                unsigned int u1 = sup32[(size_t)e1.x * 32 + sub];
                unsigned int u2 = sup32[(size_t)e2.x * 32 + sub];
                unsigned int u3 = sup32[(size_t)e3.x * 32 + sub];
                float v0 = __int_as_float(e0.y), v1 = __int_as_float(e1.y);
                float v2 = __int_as_float(e2.y), v3 = __int_as_float(e3.y);
                ax += v0 * __uint_as_float(u0 << 16);
                ay += v0 * __uint_as_float(u0 & 0xffff0000u);
                ax += v1 * __uint_as_float(u1 << 16);
                ay += v1 * __uint_as_float(u1 & 0xffff0000u);
                ax += v2 * __uint_as_float(u2 << 16);
                ay += v2 * __uint_as_float(u2 & 0xffff0000u);
                ax += v3 * __uint_as_float(u3 << 16);
                ay += v3 * __uint_as_float(u3 & 0xffff0000u);
            }
            for (; j < je; ++j) {
                int2 e = csr[j];
                unsigned int u = sup32[(size_t)e.x * 32 + sub];
                float v = __int_as_float(e.y);
                ax += v * __uint_as_float(u << 16);
                ay += v * __uint_as_float(u & 0xffff0000u);
            }
            float2 o; o.x = ax + b2.x; o.y = ay + b2.y;
            reinterpret_cast<float2*>(out)[(size_t)r * 32 + sub] = o;
        }
    }
}

// ===========================================================================
// Fallback (R1, verified): bias-init + atomic scatter (f32 support)
// ===========================================================================
__global__ __launch_bounds__(256) void init_kernel(const float* __restrict__ bias,
                                                   float* __restrict__ out, int total4) {
    int i = blockIdx.x * 256 + threadIdx.x;
    int stride = gridDim.x * 256;
    for (; i < total4; i += stride) {
        int base4 = (i * 4) & (D - 1);
        float4 bv;
        bv.x = bias[base4 + 0]; bv.y = bias[base4 + 1];
        bv.z = bias[base4 + 2]; bv.w = bias[base4 + 3];
        reinterpret_cast<float4*>(out)[i] = bv;
    }
}

__global__ __launch_bounds__(256) void scatter_kernel(const int* __restrict__ rows,
                                                      const int* __restrict__ cols,
                                                      const float* __restrict__ vals,
                                                      const float* __restrict__ support,
                                                      float* __restrict__ out, int ne) {
    const int wid  = blockIdx.x * 4 + (threadIdx.x >> 6);
    const int lane = threadIdx.x & 63;
    const int nw = gridDim.x * 4;
    for (int e = wid; e < ne; e += nw) {
        const int r = rows[e];
        const int c = cols[e];
        const float v = vals[e];
        unsafeAtomicAdd(&out[(size_t)r * D + lane], v * support[(size_t)c * D + lane]);
    }
}

extern "C" void kernel_launch(void* const* d_in, const int* in_sizes, int n_in,
                              void* d_out, int out_size, void* d_ws, size_t ws_size,
                              hipStream_t stream) {
    const float* x         = (const float*)d_in[0];
    const int*   edge_rows = (const int*)d_in[1];
    const int*   edge_cols = (const int*)d_in[2];
    const float* edge_vals = (const float*)d_in[3];
    const float* w_own     = (const float*)d_in[4];
    const float* w_nbr     = (const float*)d_in[5];
    const float* w_temp    = (const float*)d_in[6];
    const float* bias      = (const float*)d_in[7];

    float* out = (float*)d_out;
    const int n_nodes = in_sizes[0] / D;
    const int n_edges = in_sizes[1];
    const int nb = (n_nodes + RPB - 1) / RPB;

    // ---- workspace layout ----
    char* ws = (char*)d_ws;
    size_t off = 0;
    auto take = [&](size_t bytes) -> char* {
        char* p = ws + off;
        off = (off + bytes + 15) & ~(size_t)15;
        return p;
    };
    __hip_bfloat16* support = (__hip_bfloat16*)take((size_t)n_nodes * D * sizeof(__hip_bfloat16));
    int2* binned = (int2*)take((size_t)n_edges * sizeof(int2));
    int2* csr    = (int2*)take((size_t)n_edges * sizeof(int2));
    int*  rowptr = (int*) take((size_t)(n_nodes + 1) * sizeof(int));
    int*  gcnt   = (int*) take((size_t)nb * sizeof(int));
    int*  base   = (int*) take((size_t)(nb + 1) * sizeof(int));
    int*  cursor = (int*) take((size_t)nb * sizeof(int));
    const bool full_fits = (off <= ws_size) && (nb <= NBMAX) && (n_nodes <= (1 << 17));

    if (full_fits) {
        gemm_kernel<<<1024, 256, 0, stream>>>(x, w_own, w_nbr, w_temp, support, n_nodes);
        zero_kernel<<<4, 256, 0, stream>>>(gcnt, nb);
        bucket_hist_kernel<<<512, 256, 0, stream>>>(edge_rows, n_edges, gcnt, nb);
        bucket_scan_kernel<<<1, 256, 0, stream>>>(gcnt, nb, base, cursor);
        bin_scatter_kernel<<<256, 256, 0, stream>>>(edge_rows, edge_cols, edge_vals,
                                                    n_edges, cursor, nb, binned);
        // rowptr[n] = total edges (base[nb]); write via tiny kernel-free trick:
        // local_csr writes rowptr[0..n); the final sentinel comes from base[nb]
        // which bucket nb-1's block computes as je — set it here with a 1-wg copy.
        local_csr_kernel<<<nb, 256, 0, stream>>>(base, binned, rowptr, csr, n_nodes);
        hipMemcpyAsync(rowptr + n_nodes, base + nb, sizeof(int),
                       hipMemcpyDeviceToDevice, stream);
        pull2_kernel<<<2048, 256, 0, stream>>>(rowptr, csr, (const unsigned int*)support,
                                               bias, out, n_nodes);
    } else {
        // R1 fallback: f32 support + atomic scatter
        float* support_f = (float*)d_ws;
        gemm_f32_kernel<<<1024, 256, 0, stream>>>(x, w_own, w_nbr, w_temp, support_f, n_nodes);
        int total4 = (n_nodes * D) / 4;
        int blocks = (total4 + 255) / 256; if (blocks > 2048) blocks = 2048;
        init_kernel<<<blocks, 256, 0, stream>>>(bias, out, total4);
        scatter_kernel<<<2048, 256, 0, stream>>>(edge_rows, edge_cols, edge_vals,
                                                 support_f, out, n_edges);
    }
}